// Round 10
// baseline (914.336 us; speedup 1.0000x reference)
//
#include <hip/hip_runtime.h>
#include <hip/hip_bf16.h>

// RGCN 2-layer: N=50000, E=800000, R=8, 64->64->32.
// R10: fused gather+MFMA (no materialized A).
//   cvt(x->bf16), cvtW1, cvtW2 -> memset(seg) -> hist(rel-major) -> scan ->
//   scatter(perm=(src<<6)|dst&63) ->
//   fused1: hbf = bf16(relu([mean-agg_r(xbf)|xbf] @ WT1 + b1))
//   fused2: out = [mean-agg_r(hbf)|hbf] @ WT2 + b2     (fp32)
// Per (64-node tile, rel) phase: zero fp32 LDS tile -> 8 waves consume the
// contiguous perm run (full wave per edge, 4-deep, ds_add_f32) -> MFMA
// 16x16x32 with mean-scale folded into the A-frag cvt. ws ~18MB.

#define NN 50000
#define NE 800000
#define NR 8
#define NPR (NN * NR)              // rel-major: id = r*NN + dst
#define NBLK ((NPR + 1023) / 1024)

typedef __attribute__((ext_vector_type(8))) short short8v;
typedef __attribute__((ext_vector_type(4))) float float4v;

__device__ __forceinline__ float b2f(unsigned u16) {
  return __uint_as_float(u16 << 16);
}
__device__ __forceinline__ unsigned short f2b(float f) {
  __hip_bfloat16 h = __float2bfloat16(f);  // RNE, hardware cvt
  return *reinterpret_cast<unsigned short*>(&h);
}

// ---- fp32 -> bf16 bulk convert ----------------------------------------------
__global__ __launch_bounds__(256) void k_cvt(const float* __restrict__ in,
                                             unsigned short* __restrict__ out,
                                             int n4) {
  int i = blockIdx.x * 256 + threadIdx.x;
  if (i < n4) {
    float4 v = ((const float4*)in)[i];
    ushort4 o;
    o.x = f2b(v.x); o.y = f2b(v.y); o.z = f2b(v.z); o.w = f2b(v.w);
    ((ushort4*)out)[i] = o;
  }
}

// ---- weights: WT[o][k] bf16; k<512: W[k>>6][k&63][o], else root[k-512][o] ---
__global__ __launch_bounds__(256) void k_cvtW(const float* __restrict__ W,
                                              const float* __restrict__ root,
                                              unsigned short* __restrict__ WT,
                                              int NOUT) {
  int i = blockIdx.x * 256 + threadIdx.x;
  if (i < NOUT * 576) {
    const int o = i / 576, k = i - o * 576;
    const float v = (k < 512)
        ? W[(size_t)(k >> 6) * 64 * NOUT + (size_t)(k & 63) * NOUT + o]
        : root[(size_t)(k - 512) * NOUT + o];
    WT[i] = f2b(v);
  }
}

// ---- per-(rel,dst) incoming-edge count --------------------------------------
__global__ __launch_bounds__(256) void k_hist(const int* __restrict__ dst,
                                              const int* __restrict__ et,
                                              int* __restrict__ seg) {
  int e = blockIdx.x * 256 + threadIdx.x;
  if (e < NE) atomicAdd(&seg[et[e] * NN + dst[e]], 1);
}

// ---- 3-phase exclusive scan of seg[NPR] (in place) --------------------------
__global__ __launch_bounds__(256) void k_scanA(const int* __restrict__ seg,
                                               int* __restrict__ bsum) {
  __shared__ int red[256];
  const int t = threadIdx.x;
  const int base = blockIdx.x * 1024 + t * 4;
  int s = 0;
#pragma unroll
  for (int j = 0; j < 4; ++j)
    if (base + j < NPR) s += seg[base + j];
  red[t] = s;
  __syncthreads();
  for (int off = 128; off > 0; off >>= 1) {
    if (t < off) red[t] += red[t + off];
    __syncthreads();
  }
  if (t == 0) bsum[blockIdx.x] = red[0];
}

__global__ __launch_bounds__(512) void k_scanB(const int* __restrict__ bsum,
                                               int* __restrict__ boff) {
  __shared__ int ps[512];
  const int t = threadIdx.x;
  const int v = (t < NBLK) ? bsum[t] : 0;
  ps[t] = v;
  __syncthreads();
  for (int off = 1; off < 512; off <<= 1) {
    int u = (t >= off) ? ps[t - off] : 0;
    __syncthreads();
    ps[t] += u;
    __syncthreads();
  }
  if (t < NBLK) boff[t] = ps[t] - v;  // exclusive
}

__global__ __launch_bounds__(256) void k_scanC(int* __restrict__ seg,
                                               const int* __restrict__ boff) {
  __shared__ int ps[256];
  const int t = threadIdx.x;
  const int base = blockIdx.x * 1024 + t * 4;
  int v[4];
  int s = 0;
#pragma unroll
  for (int j = 0; j < 4; ++j) {
    v[j] = (base + j < NPR) ? seg[base + j] : 0;
    s += v[j];
  }
  ps[t] = s;
  __syncthreads();
  for (int off = 1; off < 256; off <<= 1) {
    int u = (t >= off) ? ps[t - off] : 0;
    __syncthreads();
    ps[t] += u;
    __syncthreads();
  }
  int run = ps[t] - s + boff[blockIdx.x];
#pragma unroll
  for (int j = 0; j < 4; ++j) {
    if (base + j < NPR) {
      int old = v[j];
      seg[base + j] = run;  // exclusive prefix
      run += old;
    }
  }
}

// ---- scatter: perm sorted by (rel,dst); word = (src<<6)|(dst&63) ------------
__global__ __launch_bounds__(256) void k_scatter(const int* __restrict__ src,
                                                 const int* __restrict__ dst,
                                                 const int* __restrict__ et,
                                                 int* __restrict__ seg,
                                                 unsigned* __restrict__ perm) {
  int e = blockIdx.x * 256 + threadIdx.x;
  if (e < NE) {
    int pos = atomicAdd(&seg[et[e] * NN + dst[e]], 1);
    perm[pos] = ((unsigned)src[e] << 6) | ((unsigned)dst[e] & 63u);
  }
}

// ---- fused gather+MFMA ------------------------------------------------------
// 64-node tile, 8 waves (512 thr). Wave wv: rowgroup rg=wv&3 (rows rg*16..+15),
// colhalf ch=wv>>2. Phases kt=0..7 (rels): zero Asf -> edge gather (full wave
// per edge, ds_add_f32) -> 2 MFMA k-steps (scale*cvt A-frag from LDS, B from
// WT in L2). Root phase: A-frag direct from feat (bf16 global).
// C/D: col=lane&15, row=(lane>>4)*4+j  [R9-verified].
template <int TN, bool OUTBF>
__global__ __launch_bounds__(512) void k_fused(const unsigned short* __restrict__ feat,
                                               const unsigned* __restrict__ perm,
                                               const int* __restrict__ seg,
                                               const unsigned short* __restrict__ WT,
                                               const float* __restrict__ bias,
                                               float* __restrict__ Cf,
                                               unsigned short* __restrict__ Ch) {
  __shared__ float Asf[64][68];   // [node][k], pad 68 -> <=2-way banks
  __shared__ int   segl[65];
  constexpr int NF = TN / 32;     // frags/wave: 2 (TN=64) | 1 (TN=32)
  const int tid  = (int)threadIdx.x;
  const int lane = tid & 63;
  const int wv   = tid >> 6;      // 0..7
  const int rg   = wv & 3;
  const int ch   = wv >> 2;
  const int n0   = blockIdx.x * 64;
  const int rc   = lane & 15;
  const int kq   = lane >> 4;     // 0..3
  float4v acc[NF];
#pragma unroll
  for (int f = 0; f < NF; ++f) acc[f] = (float4v){0.f, 0.f, 0.f, 0.f};

  for (int kt = 0; kt < 8; ++kt) {
    __syncthreads();  // previous phase's Asf reads done
    {
      float* p = &Asf[0][0];
      for (int i = tid; i < 64 * 68; i += 512) p[i] = 0.f;
      if (tid < 65) {
        int nn = n0 - 1 + tid;
        if (nn >= NN) nn = NN - 1;            // tail: empty segments
        const long g = (long)kt * NN + nn;    // <0 only kt==0 && n0==0 && tid==0
        segl[tid] = (g < 0) ? 0 : seg[g];
      }
    }
    __syncthreads();
    const int lo = segl[0], hi = segl[64];
    // ---- cooperative gather: full wave per edge, 4-deep ----
    for (int eb = lo + wv * 4; eb < hi; eb += 32) {
      const int rem = hi - eb;
      unsigned p0 = perm[eb], p1 = 0, p2 = 0, p3 = 0;
      if (rem > 1) p1 = perm[eb + 1];
      if (rem > 2) p2 = perm[eb + 2];
      if (rem > 3) p3 = perm[eb + 3];
      float v0 = b2f(feat[(size_t)(p0 >> 6) * 64 + lane]);
      float v1 = (rem > 1) ? b2f(feat[(size_t)(p1 >> 6) * 64 + lane]) : 0.f;
      float v2 = (rem > 2) ? b2f(feat[(size_t)(p2 >> 6) * 64 + lane]) : 0.f;
      float v3 = (rem > 3) ? b2f(feat[(size_t)(p3 >> 6) * 64 + lane]) : 0.f;
      atomicAdd(&Asf[p0 & 63u][lane], v0);
      if (rem > 1) atomicAdd(&Asf[p1 & 63u][lane], v1);
      if (rem > 2) atomicAdd(&Asf[p2 & 63u][lane], v2);
      if (rem > 3) atomicAdd(&Asf[p3 & 63u][lane], v3);
    }
    __syncthreads();
    // ---- MFMA: 2 k-steps of 32 for this rel ----
    const int mrow = rg * 16 + rc;
    const int cnt = segl[mrow + 1] - segl[mrow];
    const float inv = 1.0f / (float)(cnt < 1 ? 1 : cnt);
#pragma unroll
    for (int ks = 0; ks < 2; ++ks) {
      float av[8];
      *(float4*)&av[0] = *(const float4*)&Asf[mrow][ks * 32 + kq * 8];
      *(float4*)&av[4] = *(const float4*)&Asf[mrow][ks * 32 + kq * 8 + 4];
      short8v a;
#pragma unroll
      for (int j = 0; j < 8; ++j) a[j] = (short)f2b(av[j] * inv);
#pragma unroll
      for (int f = 0; f < NF; ++f) {
        const int col = ch * (TN / 2) + f * 16 + rc;
        const short8v b =
            *(const short8v*)(WT + (size_t)col * 576 + kt * 64 + ks * 32 + kq * 8);
        acc[f] = __builtin_amdgcn_mfma_f32_16x16x32_bf16(a, b, acc[f], 0, 0, 0);
      }
    }
  }
  // ---- root phase: k = 512..575, A-frag direct from feat ----
  {
    int arow = n0 + rg * 16 + rc;
    if (arow > NN - 1) arow = NN - 1;  // clamp; stores masked below
    const unsigned short* rp = feat + (size_t)arow * 64;
#pragma unroll
    for (int ks = 0; ks < 2; ++ks) {
      const short8v a = *(const short8v*)(rp + ks * 32 + kq * 8);
#pragma unroll
      for (int f = 0; f < NF; ++f) {
        const int col = ch * (TN / 2) + f * 16 + rc;
        const short8v b =
            *(const short8v*)(WT + (size_t)col * 576 + 512 + ks * 32 + kq * 8);
        acc[f] = __builtin_amdgcn_mfma_f32_16x16x32_bf16(a, b, acc[f], 0, 0, 0);
      }
    }
  }
  // ---- epilogue ----
  const int orow0 = n0 + rg * 16 + kq * 4;
#pragma unroll
  for (int f = 0; f < NF; ++f) {
    const int col16 = ch * (TN / 2) + f * 16 + rc;
    const float bv = bias[col16];
#pragma unroll
    for (int j = 0; j < 4; ++j) {
      const int r = orow0 + j;
      if (r < NN) {
        const float v = acc[f][j] + bv;
        if constexpr (OUTBF) {
          Ch[(size_t)r * 64 + col16] = f2b(fmaxf(v, 0.f));
        } else {
          Cf[(size_t)r * 32 + col16] = v;
        }
      }
    }
  }
}

// =============================================================================
extern "C" void kernel_launch(void* const* d_in, const int* in_sizes, int n_in,
                              void* d_out, int out_size, void* d_ws, size_t ws_size,
                              hipStream_t stream) {
  const float* x     = (const float*)d_in[0];
  const int*   ei    = (const int*)d_in[1];
  const int*   et    = (const int*)d_in[2];
  const float* W1    = (const float*)d_in[3];
  const float* root1 = (const float*)d_in[4];
  const float* b1    = (const float*)d_in[5];
  const float* W2    = (const float*)d_in[6];
  const float* root2 = (const float*)d_in[7];
  const float* b2    = (const float*)d_in[8];
  float* out = (float*)d_out;
  const int* srcA = ei;
  const int* dstA = ei + NE;

  // ws layout (~18MB)
  char* w = (char*)d_ws;
  size_t off = 0;
  int* seg  = (int*)(w + off); off += (size_t)NPR * 4;   // 1.6MB
  int* bsum = (int*)(w + off); off += (size_t)NBLK * 4;
  int* boff = (int*)(w + off); off += (size_t)NBLK * 4;
  off = (off + 15) & ~(size_t)15;
  unsigned* perm = (unsigned*)(w + off); off += (size_t)NE * 4;  // 3.2MB
  off = (off + 15) & ~(size_t)15;
  unsigned short* xbf = (unsigned short*)(w + off); off += (size_t)NN * 64 * 2; // 6.4MB
  off = (off + 15) & ~(size_t)15;
  unsigned short* hbf = (unsigned short*)(w + off); off += (size_t)NN * 64 * 2; // 6.4MB
  off = (off + 15) & ~(size_t)15;
  unsigned short* WT1 = (unsigned short*)(w + off); off += (size_t)64 * 576 * 2;
  off = (off + 15) & ~(size_t)15;
  unsigned short* WT2 = (unsigned short*)(w + off); off += (size_t)32 * 576 * 2;

  k_cvt<<<(NN * 64 / 4 + 255) / 256, 256, 0, stream>>>(x, xbf, NN * 64 / 4);
  k_cvtW<<<(64 * 576 + 255) / 256, 256, 0, stream>>>(W1, root1, WT1, 64);
  k_cvtW<<<(32 * 576 + 255) / 256, 256, 0, stream>>>(W2, root2, WT2, 32);
  hipMemsetAsync(seg, 0, (size_t)NPR * 4, stream);
  k_hist<<<(NE + 255) / 256, 256, 0, stream>>>(dstA, et, seg);
  k_scanA<<<NBLK, 256, 0, stream>>>(seg, bsum);
  k_scanB<<<1, 512, 0, stream>>>(bsum, boff);
  k_scanC<<<NBLK, 256, 0, stream>>>(seg, boff);
  k_scatter<<<(NE + 255) / 256, 256, 0, stream>>>(srcA, dstA, et, seg, perm);

  const int NB = (NN + 63) / 64;  // 782
  k_fused<64, true ><<<NB, 512, 0, stream>>>(xbf, perm, seg, WT1, b1, nullptr, hbf);
  k_fused<32, false><<<NB, 512, 0, stream>>>(hbf, perm, seg, WT2, b2, out, nullptr);
}

// Round 11
// 334.449 us; speedup vs baseline: 2.7339x; 2.7339x over previous
//
#include <hip/hip_runtime.h>
#include <hip/hip_bf16.h>

// RGCN 2-layer: N=50000, E=800000, R=8, 64->64->32.
// R11: R9's gather structure (50k independent waves -> full MLP) + in-kernel
// MFMA epilogue; no materialized A (saves 51MB write + 51MB read + 2 kernels).
//   cvt(x->bf16), cvtW1, cvtW2 -> memset(seg) -> hist(dst-major) -> scan ->
//   scatter(perm=src) ->
//   gm1: hbf = bf16(relu([agg|xbf] @ WT1 + b1))   (block=16 waves/16 nodes)
//   gm2: out = [agg|hbf] @ WT2 + b2               (fp32)
// Per block: wave w gathers node n0+w (R9 body, half-wave per edge, 4 chains)
// into LDS row; barrier; waves 0..TN/16-1 do 18 MFMA k-steps (A from LDS,
// root rows from feat, B from WT in L2). ws ~18MB.

#define NN 50000
#define NE 800000
#define NR 8
#define NPR (NN * NR)              // dst-major: id = dst*8 + rel
#define NBLK ((NPR + 1023) / 1024)

typedef __attribute__((ext_vector_type(8))) short short8v;
typedef __attribute__((ext_vector_type(4))) float float4v;

__device__ __forceinline__ float b2f(unsigned u16) {
  return __uint_as_float(u16 << 16);
}
__device__ __forceinline__ unsigned short f2b(float f) {
  __hip_bfloat16 h = __float2bfloat16(f);  // RNE, hardware cvt
  return *reinterpret_cast<unsigned short*>(&h);
}

// ---- fp32 -> bf16 bulk convert ----------------------------------------------
__global__ __launch_bounds__(256) void k_cvt(const float* __restrict__ in,
                                             unsigned short* __restrict__ out,
                                             int n4) {
  int i = blockIdx.x * 256 + threadIdx.x;
  if (i < n4) {
    float4 v = ((const float4*)in)[i];
    ushort4 o;
    o.x = f2b(v.x); o.y = f2b(v.y); o.z = f2b(v.z); o.w = f2b(v.w);
    ((ushort4*)out)[i] = o;
  }
}

// ---- weights: WT[o][k] bf16; k<512: W[k>>6][k&63][o], else root[k-512][o] ---
__global__ __launch_bounds__(256) void k_cvtW(const float* __restrict__ W,
                                              const float* __restrict__ root,
                                              unsigned short* __restrict__ WT,
                                              int NOUT) {
  int i = blockIdx.x * 256 + threadIdx.x;
  if (i < NOUT * 576) {
    const int o = i / 576, k = i - o * 576;
    const float v = (k < 512)
        ? W[(size_t)(k >> 6) * 64 * NOUT + (size_t)(k & 63) * NOUT + o]
        : root[(size_t)(k - 512) * NOUT + o];
    WT[i] = f2b(v);
  }
}

// ---- per-(dst,rel) incoming-edge count --------------------------------------
__global__ __launch_bounds__(256) void k_hist(const int* __restrict__ dst,
                                              const int* __restrict__ et,
                                              int* __restrict__ seg) {
  int e = blockIdx.x * 256 + threadIdx.x;
  if (e < NE) atomicAdd(&seg[dst[e] * NR + et[e]], 1);
}

// ---- 3-phase exclusive scan of seg[NPR] (in place) --------------------------
__global__ __launch_bounds__(256) void k_scanA(const int* __restrict__ seg,
                                               int* __restrict__ bsum) {
  __shared__ int red[256];
  const int t = threadIdx.x;
  const int base = blockIdx.x * 1024 + t * 4;
  int s = 0;
#pragma unroll
  for (int j = 0; j < 4; ++j)
    if (base + j < NPR) s += seg[base + j];
  red[t] = s;
  __syncthreads();
  for (int off = 128; off > 0; off >>= 1) {
    if (t < off) red[t] += red[t + off];
    __syncthreads();
  }
  if (t == 0) bsum[blockIdx.x] = red[0];
}

__global__ __launch_bounds__(512) void k_scanB(const int* __restrict__ bsum,
                                               int* __restrict__ boff) {
  __shared__ int ps[512];
  const int t = threadIdx.x;
  const int v = (t < NBLK) ? bsum[t] : 0;
  ps[t] = v;
  __syncthreads();
  for (int off = 1; off < 512; off <<= 1) {
    int u = (t >= off) ? ps[t - off] : 0;
    __syncthreads();
    ps[t] += u;
    __syncthreads();
  }
  if (t < NBLK) boff[t] = ps[t] - v;  // exclusive
}

__global__ __launch_bounds__(256) void k_scanC(int* __restrict__ seg,
                                               const int* __restrict__ boff) {
  __shared__ int ps[256];
  const int t = threadIdx.x;
  const int base = blockIdx.x * 1024 + t * 4;
  int v[4];
  int s = 0;
#pragma unroll
  for (int j = 0; j < 4; ++j) {
    v[j] = (base + j < NPR) ? seg[base + j] : 0;
    s += v[j];
  }
  ps[t] = s;
  __syncthreads();
  for (int off = 1; off < 256; off <<= 1) {
    int u = (t >= off) ? ps[t - off] : 0;
    __syncthreads();
    ps[t] += u;
    __syncthreads();
  }
  int run = ps[t] - s + boff[blockIdx.x];
#pragma unroll
  for (int j = 0; j < 4; ++j) {
    if (base + j < NPR) {
      int old = v[j];
      seg[base + j] = run;  // exclusive prefix
      run += old;
    }
  }
}

// ---- scatter: perm sorted by (dst,rel); seg becomes inclusive ends ----------
__global__ __launch_bounds__(256) void k_scatter(const int* __restrict__ src,
                                                 const int* __restrict__ dst,
                                                 const int* __restrict__ et,
                                                 int* __restrict__ seg,
                                                 int* __restrict__ perm) {
  int e = blockIdx.x * 256 + threadIdx.x;
  if (e < NE) {
    int pos = atomicAdd(&seg[dst[e] * NR + et[e]], 1);
    perm[pos] = src[e];
  }
}

// ---- fused gather (R9 shape) + MFMA -----------------------------------------
// Block = 1024 thr = 16 waves = 16 nodes (grid 3125, exact). Wave w gathers
// node n0+w into Alds[w] (bf16 pairs, uint[260]-padded row -> 2-way banks).
// Then waves 0..TN/16-1: 16 agg k-steps (LDS) + 2 root k-steps (feat global).
// A-frag: row=lane&15, k=(lane>>4)*8. C/D: col=lane&15, row=(lane>>4)*4+j.
template <int TN, bool OUTBF>
__global__ __launch_bounds__(1024) void k_gm(const unsigned short* __restrict__ feat,
                                             const int* __restrict__ perm,
                                             const int* __restrict__ seg,
                                             const unsigned short* __restrict__ WT,
                                             const float* __restrict__ bias,
                                             float* __restrict__ Cf,
                                             unsigned short* __restrict__ Ch) {
  __shared__ unsigned Alds[16][260];  // [node][k-pair]; 260 = 256 + 4 pad
  const int tid  = (int)threadIdx.x;
  const int lane = tid & 63;
  const int wv   = tid >> 6;          // 0..15
  const int n0   = blockIdx.x * 16;
  const int n    = n0 + wv;           // < NN always (50000 = 3125*16)
  // ---- gather: R9 k_gath body, LDS destination ----
  {
    const int half = lane >> 5, l32 = lane & 31;
    int b = 0;
    if (lane < 9) {
      const int g = n * NR - 1 + lane;
      b = (g < 0) ? 0 : seg[g];
    }
    const unsigned* __restrict__ f2 = (const unsigned*)feat;  // row = 32 uints
#pragma unroll
    for (int r = 0; r < NR; ++r) {
      const int s0 = __shfl(b, r);
      const int e0 = __shfl(b, r + 1);
      float a0 = 0.f, a1 = 0.f, c0 = 0.f, c1 = 0.f;
      int e = s0 + half;
      for (; e + 2 < e0; e += 4) {
        const unsigned p = (unsigned)perm[e];
        const unsigned q = (unsigned)perm[e + 2];
        const unsigned v = f2[(size_t)p * 32 + l32];
        const unsigned w = f2[(size_t)q * 32 + l32];
        a0 += b2f(v & 0xffffu); a1 += b2f(v >> 16);
        c0 += b2f(w & 0xffffu); c1 += b2f(w >> 16);
      }
      if (e < e0) {
        const unsigned p = (unsigned)perm[e];
        const unsigned v = f2[(size_t)p * 32 + l32];
        a0 += b2f(v & 0xffffu); a1 += b2f(v >> 16);
      }
      a0 += c0; a1 += c1;
      a0 += __shfl_down(a0, 32);
      a1 += __shfl_down(a1, 32);
      if (half == 0) {
        const int cnt = e0 - s0;
        const float inv = 1.0f / (float)(cnt < 1 ? 1 : cnt);
        Alds[wv][r * 32 + l32] =
            (unsigned)f2b(a0 * inv) | ((unsigned)f2b(a1 * inv) << 16);
      }
    }
  }
  __syncthreads();
  // ---- MFMA: waves 0..NW-1, one 16-col frag each ----
  constexpr int NW = TN / 16;  // 4 | 2
  if (wv < NW) {
    const int rc = lane & 15;       // A row / B col / C col
    const int kq = lane >> 4;       // 0..3
    const unsigned short* __restrict__ wp = WT + (size_t)(wv * 16 + rc) * 576;
    float4v acc = (float4v){0.f, 0.f, 0.f, 0.f};
#pragma unroll
    for (int kt = 0; kt < 16; ++kt) {
      const short8v a = *(const short8v*)&Alds[rc][kt * 16 + kq * 4];
      const short8v bb = *(const short8v*)(wp + kt * 32 + kq * 8);
      acc = __builtin_amdgcn_mfma_f32_16x16x32_bf16(a, bb, acc, 0, 0, 0);
    }
    // root: k = 512..575, rows direct from feat
    const unsigned short* __restrict__ rp = feat + (size_t)(n0 + rc) * 64;
#pragma unroll
    for (int ks = 0; ks < 2; ++ks) {
      const short8v a = *(const short8v*)(rp + ks * 32 + kq * 8);
      const short8v bb = *(const short8v*)(wp + 512 + ks * 32 + kq * 8);
      acc = __builtin_amdgcn_mfma_f32_16x16x32_bf16(a, bb, acc, 0, 0, 0);
    }
    // epilogue: C/D col=lane&15, row=(lane>>4)*4+j
    const int col16 = wv * 16 + rc;
    const float bv = bias[col16];
#pragma unroll
    for (int j = 0; j < 4; ++j) {
      const int r = n0 + kq * 4 + j;
      const float v = acc[j] + bv;
      if constexpr (OUTBF) {
        Ch[(size_t)r * 64 + col16] = f2b(fmaxf(v, 0.f));
      } else {
        Cf[(size_t)r * 32 + col16] = v;
      }
    }
  }
}

// =============================================================================
extern "C" void kernel_launch(void* const* d_in, const int* in_sizes, int n_in,
                              void* d_out, int out_size, void* d_ws, size_t ws_size,
                              hipStream_t stream) {
  const float* x     = (const float*)d_in[0];
  const int*   ei    = (const int*)d_in[1];
  const int*   et    = (const int*)d_in[2];
  const float* W1    = (const float*)d_in[3];
  const float* root1 = (const float*)d_in[4];
  const float* b1    = (const float*)d_in[5];
  const float* W2    = (const float*)d_in[6];
  const float* root2 = (const float*)d_in[7];
  const float* b2    = (const float*)d_in[8];
  float* out = (float*)d_out;
  const int* srcA = ei;
  const int* dstA = ei + NE;

  // ws layout (~18MB)
  char* w = (char*)d_ws;
  size_t off = 0;
  int* seg  = (int*)(w + off); off += (size_t)NPR * 4;   // 1.6MB
  int* bsum = (int*)(w + off); off += (size_t)NBLK * 4;
  int* boff = (int*)(w + off); off += (size_t)NBLK * 4;
  off = (off + 15) & ~(size_t)15;
  int* perm = (int*)(w + off); off += (size_t)NE * 4;    // 3.2MB
  off = (off + 15) & ~(size_t)15;
  unsigned short* xbf = (unsigned short*)(w + off); off += (size_t)NN * 64 * 2; // 6.4MB
  off = (off + 15) & ~(size_t)15;
  unsigned short* hbf = (unsigned short*)(w + off); off += (size_t)NN * 64 * 2; // 6.4MB
  off = (off + 15) & ~(size_t)15;
  unsigned short* WT1 = (unsigned short*)(w + off); off += (size_t)64 * 576 * 2;
  off = (off + 15) & ~(size_t)15;
  unsigned short* WT2 = (unsigned short*)(w + off); off += (size_t)32 * 576 * 2;

  k_cvt<<<(NN * 64 / 4 + 255) / 256, 256, 0, stream>>>(x, xbf, NN * 64 / 4);
  k_cvtW<<<(64 * 576 + 255) / 256, 256, 0, stream>>>(W1, root1, WT1, 64);
  k_cvtW<<<(32 * 576 + 255) / 256, 256, 0, stream>>>(W2, root2, WT2, 32);
  hipMemsetAsync(seg, 0, (size_t)NPR * 4, stream);
  k_hist<<<(NE + 255) / 256, 256, 0, stream>>>(dstA, et, seg);
  k_scanA<<<NBLK, 256, 0, stream>>>(seg, bsum);
  k_scanB<<<1, 512, 0, stream>>>(bsum, boff);
  k_scanC<<<NBLK, 256, 0, stream>>>(seg, boff);
  k_scatter<<<(NE + 255) / 256, 256, 0, stream>>>(srcA, dstA, et, seg, perm);

  const int NB = NN / 16;  // 3125 (exact)
  k_gm<64, true ><<<NB, 1024, 0, stream>>>(xbf, perm, seg, WT1, b1, nullptr, hbf);
  k_gm<32, false><<<NB, 1024, 0, stream>>>(hbf, perm, seg, WT2, b2, out, nullptr);
}